// Round 8
// baseline (285.642 us; speedup 1.0000x reference)
//
#include <hip/hip_runtime.h>

// AirFitMultiHeadDNN — R8: async double-buffered pipeline, 1 block/CU.
// R4-R7 post-mortem: dur pinned at 110-124us across VALU 18-67% and FETCH
// 82-377MB -> latency-bound, never throughput-bound. R7 fixed single-touch
// HBM (82MB) but stage->barrier->compute serializes at 2 waves/SIMD.
// R8: grid=256 blocks (1/CU, LDS-forced), each block pipelines 8 chunks of
// 256 items. f staged by __builtin_amdgcn_global_load_lds (16B) into TWO
// distinct static LDS buffers (compile-time parity -> no alias waits):
// prefetch chunk k+1 during compute of chunk k; __syncthreads' vmcnt(0)
// drain is the arrival fence and overlaps the prior compute phase.
// e loads stay direct-global (5KB/wave -> L1-resident, single-touch).
// Compute = R6's lean body: folded T (LDS, b128 rows) + M/W2/b2/Wo on the
// compile-time-index s_load/SGPR path.
// HBM floor: 168MB / 6.3TB/s = 27us. Target 28-40us.

#define HH   20
#define NEX  13
#define TST  12
#define WS_M 0
#define WS_T 640
#define NB   256                 // grid blocks (1 per CU)
#define NT   256                 // threads per block

__device__ __forceinline__ float softplus_fast(float x) {
    return fmaxf(x, 0.0f) + __logf(1.0f + __expf(-fabsf(x)));
}

// ---------------- setup: fold weights into M and T ----------------
__global__ void airfit_setup(const float* __restrict__ emb,
                             const float* __restrict__ Wf,
                             const float* __restrict__ bf,
                             const float* __restrict__ W1,
                             const float* __restrict__ b1,
                             float* __restrict__ ws)
{
    int t = blockIdx.x * 256 + threadIdx.x;
    if (t < HH * 3 * 10) {                       // M[h][c][o]
        int h = t / 30, c = (t / 10) % 3, o = t % 10;
        float a = 0.0f;
        for (int q = 0; q < 5; ++q)
            a += Wf[c * 5 + q] * W1[(h * 8 + 3 + q) * 10 + o];
        ws[WS_M + (h * 3 + c) * 10 + o] = a;
    }
    if (t < HH * NEX * 10) {                     // T[h][idx][o]
        int h = t / (NEX * 10), idx = (t / 10) % NEX, o = t % 10;
        float a = b1[h * 10 + o];
        for (int i = 0; i < 3; ++i)
            a += emb[idx * 3 + i] * W1[(h * 8 + i) * 10 + o];
        for (int q = 0; q < 5; ++q)
            a += bf[q] * W1[(h * 8 + 3 + q) * 10 + o];
        ws[WS_T + (h * NEX + idx) * TST + o] = a;
    }
}

// ---------------- async staging: global f -> LDS [c4][wave][lane] --------
__device__ __forceinline__ void prefetch_f(float4 (*__restrict__ sf)[4][64],
                                           const float* __restrict__ f,
                                           int chunk, int tid, int B)
{
    const int w = tid >> 6, l = tid & 63;
    int item = chunk * NT + (w << 6) + l;
    if (item > B - 1) item = B - 1;              // clamp: safe garbage
    const float4* gp = reinterpret_cast<const float4*>(f) + (size_t)item * 15;
#pragma unroll
    for (int k = 0; k < 15; ++k) {
        __builtin_amdgcn_global_load_lds(
            (const __attribute__((address_space(1))) void*)(gp + k),
            (__attribute__((address_space(3))) void*)(&sf[k][w][0]),
            16, 0, 0);
    }
}

// ---------------- compute one 256-item chunk (R6 lean body) --------------
__device__ __forceinline__ void compute_chunk(
    const float4 (*__restrict__ sf)[4][64],
    const float* __restrict__ s_T, int chunk, int tid,
    const int* __restrict__ e,  const float* __restrict__ M,
    const float* __restrict__ W2, const float* __restrict__ b2,
    const float* __restrict__ Wo, float bo0,
    float* __restrict__ out, int B)
{
    const int w = tid >> 6, l = tid & 63;
    const int item = chunk * NT + tid;
    if (item >= B) return;

    const int4* ep = reinterpret_cast<const int4*>(e + (size_t)item * HH);
    float acc = bo0;

#pragma unroll
    for (int g = 0; g < 5; ++g) {
        int4 iv = ep[g];                         // stride-80B, L1-covered
        int ii[4] = { iv.x, iv.y, iv.z, iv.w };
        float4 fA = sf[3 * g + 0][w][l];         // conflict-free b128
        float4 fB = sf[3 * g + 1][w][l];
        float4 fC = sf[3 * g + 2][w][l];
        float ff[12] = { fA.x, fA.y, fA.z, fA.w,
                         fB.x, fB.y, fB.z, fB.w,
                         fC.x, fC.y, fC.z, fC.w };

#pragma unroll
        for (int t = 0; t < 4; ++t) {
            const int h = 4 * g + t;             // compile-time constant
            const float* Trow = s_T + (h * NEX + ii[t]) * TST;
            float4 t0 = *reinterpret_cast<const float4*>(Trow);
            float4 t1 = *reinterpret_cast<const float4*>(Trow + 4);
            float2 t2 = *reinterpret_cast<const float2*>(Trow + 8);
            float pre[10] = { t0.x, t0.y, t0.z, t0.w,
                              t1.x, t1.y, t1.z, t1.w, t2.x, t2.y };

            float g0 = ff[3 * t + 0], g1 = ff[3 * t + 1], g2 = ff[3 * t + 2];
            float hacc = b2[h];
#pragma unroll
            for (int o = 0; o < 10; ++o) {
                float a = pre[o];
                a = fmaf(g0, M[(h * 3 + 0) * 10 + o], a);
                a = fmaf(g1, M[(h * 3 + 1) * 10 + o], a);
                a = fmaf(g2, M[(h * 3 + 2) * 10 + o], a);
                a = fmaxf(a, 0.01f * a);         // leaky_relu
                hacc = fmaf(a, W2[h * 10 + o], hacc);
            }
            acc = fmaf(softplus_fast(hacc), Wo[h], acc);
        }
    }

    out[item] = acc;
}

// ---------------- main ----------------
__global__ __launch_bounds__(NT) void airfit_kernel(
    const int*   __restrict__ e,   const float* __restrict__ f,
    const float* __restrict__ ws,  const float* __restrict__ W2,
    const float* __restrict__ b2,  const float* __restrict__ Wo,
    const float* __restrict__ bo,  float* __restrict__ out, int B)
{
    __shared__ float4 s_fA[15][4][64];           // 61,440 B
    __shared__ float4 s_fB[15][4][64];           // 61,440 B
    __shared__ float  s_T[HH * NEX * TST];       // 12,480 B  => 132.2 KB

    const int tid = threadIdx.x;
    for (int t = tid; t < HH * NEX * TST; t += NT)
        s_T[t] = ws[WS_T + t];

    const int chunks = (B + NT - 1) / NT;
    const float* M  = ws + WS_M;
    const float bo0 = bo[0];

    int c = blockIdx.x;
    if (c < chunks) prefetch_f(s_fA, f, c, tid, B);
    __syncthreads();                             // T + first f arrived

    for (; c < chunks; c += 2 * NB) {
        int cB = c + NB;
        if (cB < chunks) prefetch_f(s_fB, f, cB, tid, B);
        compute_chunk(s_fA, s_T, c, tid, e, M, W2, b2, Wo, bo0, out, B);
        __syncthreads();                         // cB arrived; s_fA reusable

        int cA = c + 2 * NB;
        if (cA < chunks) prefetch_f(s_fA, f, cA, tid, B);
        if (cB < chunks)
            compute_chunk(s_fB, s_T, cB, tid, e, M, W2, b2, Wo, bo0, out, B);
        __syncthreads();                         // cA arrived; s_fB reusable
    }
}

extern "C" void kernel_launch(void* const* d_in, const int* in_sizes, int n_in,
                              void* d_out, int out_size, void* d_ws, size_t ws_size,
                              hipStream_t stream) {
    const int*   e   = (const int*)  d_in[0];
    const float* f   = (const float*)d_in[1];
    const float* emb = (const float*)d_in[2];
    const float* Wf  = (const float*)d_in[3];
    const float* bf  = (const float*)d_in[4];
    const float* W1  = (const float*)d_in[5];
    const float* b1  = (const float*)d_in[6];
    const float* W2  = (const float*)d_in[7];
    const float* b2  = (const float*)d_in[8];
    const float* Wo  = (const float*)d_in[9];
    const float* bo  = (const float*)d_in[10];
    float* out = (float*)d_out;
    float* ws  = (float*)d_ws;

    int B = in_sizes[0] / HH;                    // e is (B, 20)

    airfit_setup<<<11, 256, 0, stream>>>(emb, Wf, bf, W1, b1, ws);
    airfit_kernel<<<NB, NT, 0, stream>>>(e, f, ws, W2, b2, Wo, bo, out, B);
}

// Round 9
// 251.737 us; speedup vs baseline: 1.1347x; 1.1347x over previous
//
#include <hip/hip_runtime.h>

// AirFitMultiHeadDNN — R9: R7's single-touch staging + R6's lean body at
// DOUBLE the occupancy (16 waves/CU).
// Evidence R1-R8: VALU-busy only 22-29us; walls are (a) scattered L2-fill
// ~3.2TB/s when loading strided rows directly (R6: 377MB), (b) latency
// exposure at 4-8 waves/CU when LDS crushes occupancy (R7/R8).
// R9 shrinks LDS: f staged fp16 (half4; err ~5e-4 << 3.9e-2 threshold),
// e packed 4-bit (idx 0..12), T fp32. 512-item/512-thread blocks:
//   61,440(f) + 6,144(e) + 12,480(T) = 80,064 B -> 2 blocks/CU = 16 waves.
// Staging = lane-contiguous float4/int4 streams (single-touch, high-BW).
// Compute: h1 = leaky(T[h][idx] + f·M[h]); s = softplus(h1·W2+b2);
// out = sum s·Wo + bo.  M/W2/b2/Wo on compile-time-index s_load path.

#define HH   20
#define NEX  13
#define TST  12
#define WS_M 0
#define WS_T 640
#define NT   512                 // threads = items per block

typedef __attribute__((ext_vector_type(4))) _Float16 half4;

__device__ __forceinline__ float softplus_fast(float x) {
    return fmaxf(x, 0.0f) + __logf(1.0f + __expf(-fabsf(x)));
}

// ---------------- setup: fold weights into M and T ----------------
__global__ void airfit_setup(const float* __restrict__ emb,
                             const float* __restrict__ Wf,
                             const float* __restrict__ bf,
                             const float* __restrict__ W1,
                             const float* __restrict__ b1,
                             float* __restrict__ ws)
{
    int t = blockIdx.x * 256 + threadIdx.x;
    if (t < HH * 3 * 10) {                       // M[h][c][o]
        int h = t / 30, c = (t / 10) % 3, o = t % 10;
        float a = 0.0f;
        for (int q = 0; q < 5; ++q)
            a += Wf[c * 5 + q] * W1[(h * 8 + 3 + q) * 10 + o];
        ws[WS_M + (h * 3 + c) * 10 + o] = a;
    }
    if (t < HH * NEX * 10) {                     // T[h][idx][o]
        int h = t / (NEX * 10), idx = (t / 10) % NEX, o = t % 10;
        float a = b1[h * 10 + o];
        for (int i = 0; i < 3; ++i)
            a += emb[idx * 3 + i] * W1[(h * 8 + i) * 10 + o];
        for (int q = 0; q < 5; ++q)
            a += bf[q] * W1[(h * 8 + 3 + q) * 10 + o];
        ws[WS_T + (h * NEX + idx) * TST + o] = a;
    }
}

// ---------------- main ----------------
__global__ __launch_bounds__(NT, 4) void airfit_kernel(
    const int*   __restrict__ e,   const float* __restrict__ f,
    const float* __restrict__ ws,  const float* __restrict__ W2,
    const float* __restrict__ b2,  const float* __restrict__ Wo,
    const float* __restrict__ bo,  float* __restrict__ out, int B)
{
    __shared__ half4          s_fh[15][NT];      // 61,440 B (fp16 f)
    __shared__ unsigned short s_e[NT * 6];       //  6,144 B (4-bit idx)
    __shared__ float          s_T[HH * NEX * TST]; // 12,480 B => 80,064 B

    const int tid  = threadIdx.x;
    const int base = blockIdx.x * NT;
    const int nIt  = min(NT, B - base);

    // ---- stage T (ws is L2-hot after setup) ----
    for (int t = tid; t < HH * NEX * TST; t += NT)
        s_T[t] = ws[WS_T + t];

    // ---- stage f: lane-contiguous float4 stream -> fp16 SoA ----
    {
        const float4* fg = reinterpret_cast<const float4*>(f) + (size_t)base * 15;
        const int total4 = nIt * 15;
#pragma unroll
        for (int k = 0; k < 15; ++k) {
            int idx = tid + NT * k;
            if (idx < total4) {
                float4 v = fg[idx];
                int item = idx / 15, c4 = idx - item * 15;
                half4 hv = { (_Float16)v.x, (_Float16)v.y,
                             (_Float16)v.z, (_Float16)v.w };
                s_fh[c4][item] = hv;
            }
        }
    }

    // ---- stage e: lane-contiguous int4 stream -> 4-bit packed ----
    {
        const int4* eg = reinterpret_cast<const int4*>(e) + (size_t)base * 5;
        const int total4 = nIt * 5;
#pragma unroll
        for (int k = 0; k < 5; ++k) {
            int idx = tid + NT * k;
            if (idx < total4) {
                int4 iv = eg[idx];
                int item = idx / 5, g = idx - item * 5;
                unsigned p = (unsigned)iv.x | ((unsigned)iv.y << 4) |
                             ((unsigned)iv.z << 8) | ((unsigned)iv.w << 12);
                s_e[item * 6 + g] = (unsigned short)p;
            }
        }
    }

    __syncthreads();                             // only barrier

    if (tid >= nIt) return;
    const float* M = ws + WS_M;

    // 3 dwords hold this item's 20 indices (4 bits each)
    const unsigned* e32 = reinterpret_cast<const unsigned*>(s_e);
    unsigned ew[3] = { e32[tid * 3 + 0], e32[tid * 3 + 1], e32[tid * 3 + 2] };

    float acc = bo[0];

#pragma unroll
    for (int g = 0; g < 5; ++g) {
        half4 a0 = s_fh[3 * g + 0][tid];         // consecutive-lane b64
        half4 a1 = s_fh[3 * g + 1][tid];
        half4 a2 = s_fh[3 * g + 2][tid];
        float ff[12] = { (float)a0.x, (float)a0.y, (float)a0.z, (float)a0.w,
                         (float)a1.x, (float)a1.y, (float)a1.z, (float)a1.w,
                         (float)a2.x, (float)a2.y, (float)a2.z, (float)a2.w };
        unsigned gw  = ew[g >> 1] >> ((g & 1) * 16);   // 16-bit nibble group

#pragma unroll
        for (int t = 0; t < 4; ++t) {
            const int h = 4 * g + t;             // compile-time constant
            int idx = (gw >> (4 * t)) & 0xf;

            const float* Trow = s_T + (h * NEX + idx) * TST;
            float4 t0 = *reinterpret_cast<const float4*>(Trow);
            float4 t1 = *reinterpret_cast<const float4*>(Trow + 4);
            float2 t2 = *reinterpret_cast<const float2*>(Trow + 8);
            float pre[10] = { t0.x, t0.y, t0.z, t0.w,
                              t1.x, t1.y, t1.z, t1.w, t2.x, t2.y };

            float g0 = ff[3 * t + 0], g1 = ff[3 * t + 1], g2 = ff[3 * t + 2];
            float hacc = b2[h];
#pragma unroll
            for (int o = 0; o < 10; ++o) {
                float a = pre[o];
                a = fmaf(g0, M[(h * 3 + 0) * 10 + o], a);
                a = fmaf(g1, M[(h * 3 + 1) * 10 + o], a);
                a = fmaf(g2, M[(h * 3 + 2) * 10 + o], a);
                a = fmaxf(a, 0.01f * a);         // leaky_relu
                hacc = fmaf(a, W2[h * 10 + o], hacc);
            }
            acc = fmaf(softplus_fast(hacc), Wo[h], acc);
        }
    }

    out[base + tid] = acc;
}

extern "C" void kernel_launch(void* const* d_in, const int* in_sizes, int n_in,
                              void* d_out, int out_size, void* d_ws, size_t ws_size,
                              hipStream_t stream) {
    const int*   e   = (const int*)  d_in[0];
    const float* f   = (const float*)d_in[1];
    const float* emb = (const float*)d_in[2];
    const float* Wf  = (const float*)d_in[3];
    const float* bf  = (const float*)d_in[4];
    const float* W1  = (const float*)d_in[5];
    const float* b1  = (const float*)d_in[6];
    const float* W2  = (const float*)d_in[7];
    const float* b2  = (const float*)d_in[8];
    const float* Wo  = (const float*)d_in[9];
    const float* bo  = (const float*)d_in[10];
    float* out = (float*)d_out;
    float* ws  = (float*)d_ws;

    int B = in_sizes[0] / HH;                    // e is (B, 20)

    airfit_setup<<<11, 256, 0, stream>>>(emb, Wf, bf, W1, b1, ws);

    int blocks = (B + NT - 1) / NT;
    airfit_kernel<<<blocks, NT, 0, stream>>>(e, f, ws, W2, b2, Wo, bo, out, B);
}